// Round 7
// baseline (5821.722 us; speedup 1.0000x reference)
//
#include <hip/hip_runtime.h>
#include <hip/hip_bf16.h>

typedef unsigned short u16;
typedef unsigned int   u32;
typedef unsigned long long u64;
typedef short short8 __attribute__((ext_vector_type(8)));
typedef float f32x4  __attribute__((ext_vector_type(4)));
typedef u16   u16x4  __attribute__((ext_vector_type(4)));
typedef u32   u32x4  __attribute__((ext_vector_type(4)));

#define T_STEPS 512
#define BATCH   64
#define HD      1024
#define NBLK    128    // 32 gate-cols per block, 1 block/CU (LDS-bound)
#define NTHR    256
#define NCOL    32
#define WKS     2056   // K-stride in LDS elems: 2048 + 8 pad (16B-aligned)
#define HBUF_E  (BATCH * HD)   // elems per h buffer (128 KB)
#define POISON  0xFFFFFFFFu    // two bf16 NaNs; |h|<1 so never produced

// LDS layout (bytes). c-state lives in registers (wave-private rows).
#define W_BYTES    (NCOL * WKS * 2)       // 131584
#define G_OFF      W_BYTES
#define G_STRIDE   33
#define G_BYTES    (BATCH * G_STRIDE * 4) // 8448
#define B_OFF      (G_OFF + G_BYTES)
#define B_BYTES    (NCOL * 4)             // 128
#define F_OFF      (B_OFF + B_BYTES)
#define SMEM_BYTES (F_OFF + 16)           // ~140 KB < 160 KB -> 1 block/CU

__device__ __forceinline__ float sigm(float x) { return 1.f / (1.f + __expf(-x)); }
__device__ __forceinline__ float tanh_(float x) {
    float ax = __builtin_fabsf(x);
    float e  = __expf(-2.f * ax);
    float r  = (1.f - e) / (1.f + e);
    return x < 0.f ? -r : r;
}
__device__ __forceinline__ short bfb(float f) {          // fp32 -> bf16 bits (RNE)
    __hip_bfloat16 h = __float2bfloat16(f);
    return *(short*)&h;
}

// Dtype probe: packed-bf16 x -> low-u16 exponent in [100,140] ~always;
// fp32 x -> mantissa junk, ~uniform. 18-sigma separation at threshold 128.
__device__ int detect_bf16(const u32* __restrict__ x) {
    int c = 0;
#pragma unroll 8
    for (int i = 0; i < 256; ++i) {
        u32 e = (x[i] >> 7) & 0xFF;
        c += (e >= 100 && e <= 140) ? 1 : 0;
    }
    return c >= 128;
}

// Prologue: if x is fp32 and ws has room, pre-convert x -> bf16 once.
extern "C" __global__ void __launch_bounds__(256)
cvt_x_kernel(const void* __restrict__ x, u16* __restrict__ xb, int n4)
{
    __shared__ int flg;
    if (threadIdx.x == 0) flg = detect_bf16((const u32*)x);
    __syncthreads();
    if (flg) return;
    const float4* xf = (const float4*)x;
    u16x4* xo = (u16x4*)xb;
    for (int i = blockIdx.x * blockDim.x + threadIdx.x; i < n4;
         i += gridDim.x * blockDim.x) {
        float4 v = xf[i];
        u16x4 o;
        o[0] = (u16)bfb(v.x); o[1] = (u16)bfb(v.y);
        o[2] = (u16)bfb(v.z); o[3] = (u16)bfb(v.w);
        xo[i] = o;
    }
}

// Poison the h-ring each launch. Plain stores; kernel-end release + stream
// order + lstm's entry buffer_inv make them visible to lstm's loads. This
// also kills the replay hazard (previous launch's identical h values would
// otherwise masquerade as fresh data).
extern "C" __global__ void __launch_bounds__(256)
poison_ring_kernel(u32x4* __restrict__ ring, long n)
{
    u32x4 p = {POISON, POISON, POISON, POISON};
    for (long i = (long)blockIdx.x * blockDim.x + threadIdx.x; i < n;
         i += (long)gridDim.x * blockDim.x)
        ring[i] = p;
}

union Frag16 { u64 q[2]; short8 s8[1]; };
union HF     { short8 s8; u32 w[4]; u64 q[2]; };

// Legacy (non-ring) chunk load: 8-B agent-scope atomic loads from the
// coherence point, OLD dense row-major layout. Correctness fallback only.
__device__ __forceinline__ void load_chunk_atomic(const u16* hp, int c, Frag16* buf) {
#pragma unroll
    for (int it = 0; it < 4; ++it) {
        const u16* ptr = hp + c * 128 + it * 32;
        buf[it].q[0] = __hip_atomic_load((const u64*)ptr, __ATOMIC_RELAXED,
                                         __HIP_MEMORY_SCOPE_AGENT);
        buf[it].q[1] = __hip_atomic_load((const u64*)(ptr + 4), __ATOMIC_RELAXED,
                                         __HIP_MEMORY_SCOPE_AGENT);
    }
}

// Per-lane: all 16 dwords of this chunk non-poison? Wave-uniform verdict.
// u32 stores are atomic per-dword -> no torn fragments possible.
__device__ __forceinline__ int chunk_clean(const HF* b) {
    u32 ok = 1;
#pragma unroll
    for (int it = 0; it < 4; ++it)
#pragma unroll
        for (int d = 0; d < 4; ++d)
            ok &= (b[it].w[d] != POISON) ? 1u : 0u;
    return __all((int)ok);
}

// ---- forced-issue primitives (T4 / m218 pattern, rule #18) — proven R2/R6 ---
#define LDX(dst, base, OFFSTR) \
    asm volatile("global_load_dwordx4 %0, %1, off offset:" OFFSTR \
                 : "=v"(dst) : "v"(base))

// Block-major ring layout: h[t][kblk][row][8cols], kblk = k/8 (owning block).
// Chunk c covers kblks cc*16..cc*16+16; lane fragment for iter it is
// kblk = cc*16 + it*4 + quad, 16 B at row arow. hp pre-adds quad*512 + arow*8
// (elems). Chunk stride 16 KB; iter stride 4 KB. 13-bit signed imm caps at
// 4095, so two bases with offsets -4096/0.
#define ISSUE_CHUNK(ci) do {                                            \
    const int cc_ = (c0 + (ci)) & 7;                                    \
    u64 bA_ = (u64)(hp + (size_t)cc_ * 8192) + 4096;                    \
    u64 bB_ = bA_ + 8192;                                               \
    LDX(buf[ci][0].s8, bA_, "-4096"); LDX(buf[ci][1].s8, bA_, "0");     \
    LDX(buf[ci][2].s8, bB_, "-4096"); LDX(buf[ci][3].s8, bB_, "0");     \
} while (0)

#define MFMA_CHUNK(ci) do {                                             \
    const int cc_ = (c0 + (ci)) & 7;                                    \
    const u16* wA_ = wb0 + 1024 + cc_ * 128;                            \
    const u16* wB_ = wb1 + 1024 + cc_ * 128;                            \
    short8 b0_, b1_;                                                    \
    b0_ = *(const short8*)(wA_);       b1_ = *(const short8*)(wB_);     \
    a0 = __builtin_amdgcn_mfma_f32_16x16x32_bf16(buf[ci][0].s8, b0_, a0, 0, 0, 0); \
    a1 = __builtin_amdgcn_mfma_f32_16x16x32_bf16(buf[ci][0].s8, b1_, a1, 0, 0, 0); \
    b0_ = *(const short8*)(wA_ + 32);  b1_ = *(const short8*)(wB_ + 32);\
    a0 = __builtin_amdgcn_mfma_f32_16x16x32_bf16(buf[ci][1].s8, b0_, a0, 0, 0, 0); \
    a1 = __builtin_amdgcn_mfma_f32_16x16x32_bf16(buf[ci][1].s8, b1_, a1, 0, 0, 0); \
    b0_ = *(const short8*)(wA_ + 64);  b1_ = *(const short8*)(wB_ + 64);\
    a0 = __builtin_amdgcn_mfma_f32_16x16x32_bf16(buf[ci][2].s8, b0_, a0, 0, 0, 0); \
    a1 = __builtin_amdgcn_mfma_f32_16x16x32_bf16(buf[ci][2].s8, b1_, a1, 0, 0, 0); \
    b0_ = *(const short8*)(wA_ + 96);  b1_ = *(const short8*)(wB_ + 96);\
    a0 = __builtin_amdgcn_mfma_f32_16x16x32_bf16(buf[ci][3].s8, b0_, a0, 0, 0, 0); \
    a1 = __builtin_amdgcn_mfma_f32_16x16x32_bf16(buf[ci][3].s8, b1_, a1, 0, 0, 0); \
} while (0)

// Counted drain for chunk ci, then poison check: clean -> MFMA immediately
// (fine-grained skew absorption), dirty -> defer to the atomic-retry loop.
#define HCHK(ci, VMSTR) do {                                            \
    asm volatile("s_waitcnt vmcnt(" VMSTR ")");                         \
    __builtin_amdgcn_sched_barrier(0);                                  \
    if (chunk_clean(buf[ci])) { MFMA_CHUNK(ci); }                       \
    else { dirty |= (1u << (ci)); }                                     \
} while (0)

extern "C" __global__ void __launch_bounds__(NTHR, 1)
lstm_persistent(const void* __restrict__ x,
                const void* __restrict__ Wxf, const void* __restrict__ Wxi,
                const void* __restrict__ Wxg, const void* __restrict__ Wxo,
                const void* __restrict__ Whf, const void* __restrict__ Whi,
                const void* __restrict__ Whg, const void* __restrict__ Who,
                const void* __restrict__ bxf, const void* __restrict__ bxi,
                const void* __restrict__ bxg, const void* __restrict__ bxo,
                const void* __restrict__ bhf, const void* __restrict__ bhi,
                const void* __restrict__ bhg, const void* __restrict__ bho,
                u16* __restrict__ hring, int ring_on,
                u16* __restrict__ xb, int* __restrict__ flags,
                void* __restrict__ outv)
{
    // One-time agent acquire: buffer_inv clears L1/L2 of poison-fill residue
    // and prior-replay ring lines.
    __builtin_amdgcn_fence(__ATOMIC_ACQUIRE, "agent");

    extern __shared__ char smem[];
    u16*   w_lds = (u16*)smem;
    float* g_lds = (float*)(smem + G_OFF);
    float* b_lds = (float*)(smem + B_OFF);
    int*   f_lds = (int*)(smem + F_OFF);

    const int tid = threadIdx.x;
    const int blk = blockIdx.x;

    if (tid == 0) f_lds[0] = detect_bf16((const u32*)x);
    __syncthreads();
    const int bf16mode = f_lds[0];

    // ---- Stage weight slice once (bf16): cols [8*blk, 8*blk+8) of gates f,i,g,o.
    //      LDS: [gate-col][K], K = 1024 x-side then 1024 h-side, k-contiguous.
    {
        const int gate = tid >> 6;   // wave-uniform
        const int kb   = tid & 63;
        const void* WX[4] = {Wxf, Wxi, Wxg, Wxo};
        const void* WH[4] = {Whf, Whi, Whg, Who};
        for (int it = 0; it < 16; ++it) {
            int k = it * 64 + kb;
            u16 vx[8], vh[8];
            if (bf16mode) {
                short8 a = *(const short8*)((const u16*)WX[gate] + (size_t)k * HD + blk * 8);
                short8 b = *(const short8*)((const u16*)WH[gate] + (size_t)k * HD + blk * 8);
#pragma unroll
                for (int ci = 0; ci < 8; ++ci) { vx[ci] = (u16)a[ci]; vh[ci] = (u16)b[ci]; }
            } else {
                const float* px = (const float*)WX[gate] + (size_t)k * HD + blk * 8;
                const float* ph = (const float*)WH[gate] + (size_t)k * HD + blk * 8;
                float4 a0 = *(const float4*)px, a1 = *(const float4*)(px + 4);
                float4 b0 = *(const float4*)ph, b1 = *(const float4*)(ph + 4);
                vx[0]=(u16)bfb(a0.x); vx[1]=(u16)bfb(a0.y); vx[2]=(u16)bfb(a0.z); vx[3]=(u16)bfb(a0.w);
                vx[4]=(u16)bfb(a1.x); vx[5]=(u16)bfb(a1.y); vx[6]=(u16)bfb(a1.z); vx[7]=(u16)bfb(a1.w);
                vh[0]=(u16)bfb(b0.x); vh[1]=(u16)bfb(b0.y); vh[2]=(u16)bfb(b0.z); vh[3]=(u16)bfb(b0.w);
                vh[4]=(u16)bfb(b1.x); vh[5]=(u16)bfb(b1.y); vh[6]=(u16)bfb(b1.z); vh[7]=(u16)bfb(b1.w);
            }
#pragma unroll
            for (int ci = 0; ci < 8; ++ci) {
                w_lds[(gate * 8 + ci) * WKS + k]        = vx[ci];
                w_lds[(gate * 8 + ci) * WKS + 1024 + k] = vh[ci];
            }
        }
    }
    if (tid < NCOL) {
        const void* BX[4] = {bxf, bxi, bxg, bxo};
        const void* BH[4] = {bhf, bhi, bhg, bho};
        int gate = tid >> 3, hc = blk * 8 + (tid & 7);
        float v;
        if (bf16mode)
            v = __bfloat162float(((const __hip_bfloat16*)BX[gate])[hc]) +
                __bfloat162float(((const __hip_bfloat16*)BH[gate])[hc]);
        else
            v = ((const float*)BX[gate])[hc] + ((const float*)BH[gate])[hc];
        b_lds[tid] = v;
    }
    __syncthreads();   // last block-wide sync: w_lds/b_lds now read-only

    // MFMA 16x16x32 bf16: A[m=lane&15][k=quad*8+j], B[k=quad*8+j][n=lane&15],
    // C/D: col=lane&15, row=quad*4+reg  [m89/m91].
    const int wv   = tid >> 6;       // wave = row-class (16 batch rows)
    const int lane = tid & 63;
    const int c16  = lane & 15;
    const int quad = lane >> 4;
    const int arow = wv * 16 + c16;  // batch row this lane loads for A

    const int use16 = bf16mode || (xb != nullptr);
    const u16*   x16l = nullptr;
    const float* xf_l = nullptr;
    if (use16) {
        const u16* x16 = bf16mode ? (const u16*)x : xb;
        x16l = x16 + (size_t)arow * T_STEPS * HD + quad * 8;
    } else {
        xf_l = (const float*)x + (size_t)arow * T_STEPS * HD + quad * 8;
    }
    const u16* wb0 = w_lds + c16 * WKS + quad * 8;         // N-subtile 0: cols 0-15
    const u16* wb1 = w_lds + (16 + c16) * WKS + quad * 8;  // N-subtile 1: cols 16-31

    // gate-phase mapping (wave-private rows): row = wv*16 + (lane>>2),
    // two adjacent local h-cols hl0, hl0+1.
    const int grow = wv * 16 + (lane >> 2);
    const int hl0  = (lane & 3) * 2;
    float bias[8];
#pragma unroll
    for (int g = 0; g < 4; ++g) {
        bias[g * 2]     = b_lds[g * 8 + hl0];
        bias[g * 2 + 1] = b_lds[g * 8 + hl0 + 1];
    }
    float creg[2] = {0.f, 0.f};      // c-state lives in registers (c0 = 0)

    const int c0 = blk >> 4;         // chunk-order rotation (de-burst)

    // x-side partials for t=0 (h-independent)
    f32x4 ax0 = {0.f,0.f,0.f,0.f}, ax1 = {0.f,0.f,0.f,0.f};
    if (use16) {
        const u16* xp = x16l;
#pragma unroll 8
        for (int kc = 0; kc < 32; ++kc) {
            short8 a  = *(const short8*)(xp + kc * 32);
            short8 b0 = *(const short8*)(wb0 + kc * 32);
            short8 b1 = *(const short8*)(wb1 + kc * 32);
            ax0 = __builtin_amdgcn_mfma_f32_16x16x32_bf16(a, b0, ax0, 0, 0, 0);
            ax1 = __builtin_amdgcn_mfma_f32_16x16x32_bf16(a, b1, ax1, 0, 0, 0);
        }
    } else {
        const float* xp = xf_l;
#pragma unroll 4
        for (int kc = 0; kc < 32; ++kc) {
            float4 fa = *(const float4*)(xp + kc * 32);
            float4 fb = *(const float4*)(xp + kc * 32 + 4);
            short8 a = {bfb(fa.x), bfb(fa.y), bfb(fa.z), bfb(fa.w),
                        bfb(fb.x), bfb(fb.y), bfb(fb.z), bfb(fb.w)};
            short8 b0 = *(const short8*)(wb0 + kc * 32);
            short8 b1 = *(const short8*)(wb1 + kc * 32);
            ax0 = __builtin_amdgcn_mfma_f32_16x16x32_bf16(a, b0, ax0, 0, 0, 0);
            ax1 = __builtin_amdgcn_mfma_f32_16x16x32_bf16(a, b1, ax1, 0, 0, 0);
        }
    }

    for (int t = 0; t < T_STEPS; ++t) {
        f32x4 a0 = ax0, a1 = ax1;

        if (t > 0) {
            if (ring_on) {
                // ---- NO FLAGS: the data is its own readiness signal. Blast
                //      all 32 cached loads (block-major, full lines), counted
                //      drain per chunk, poison-check; clean -> MFMA now,
                //      dirty -> atomic-load retry (always reads the coherence
                //      point -> stale-L2 livelock structurally impossible;
                //      progress by induction from buffer 0).
                const u16* hp = hring + (size_t)(t - 1) * HBUF_E
                              + quad * 512 + arow * 8;
                HF buf[8][4];
                u32 dirty = 0;
                asm volatile("s_waitcnt vmcnt(0)");   // drain x loads + h stores
                ISSUE_CHUNK(0); ISSUE_CHUNK(1); ISSUE_CHUNK(2); ISSUE_CHUNK(3);
                ISSUE_CHUNK(4); ISSUE_CHUNK(5); ISSUE_CHUNK(6); ISSUE_CHUNK(7);
                HCHK(0, "28"); HCHK(1, "24"); HCHK(2, "20"); HCHK(3, "16");
                HCHK(4, "12"); HCHK(5, "8");  HCHK(6, "4");  HCHK(7, "0");
                while (dirty) {                       // wave-uniform mask
#pragma unroll
                    for (int ci = 0; ci < 8; ++ci) {
                        if (dirty & (1u << ci)) {
                            const int cc_ = (c0 + ci) & 7;
#pragma unroll
                            for (int it = 0; it < 4; ++it) {
                                const u16* p = hp + (size_t)cc_ * 8192 + it * 2048;
                                buf[ci][it].q[0] = __hip_atomic_load(
                                    (const u64*)p, __ATOMIC_RELAXED,
                                    __HIP_MEMORY_SCOPE_AGENT);
                                buf[ci][it].q[1] = __hip_atomic_load(
                                    (const u64*)(p + 4), __ATOMIC_RELAXED,
                                    __HIP_MEMORY_SCOPE_AGENT);
                            }
                            if (chunk_clean(buf[ci])) {
                                MFMA_CHUNK(ci);
                                dirty &= ~(1u << ci);
                            }
                        }
                    }
                    if (dirty) __builtin_amdgcn_s_sleep(1);
                }
            } else {
                // legacy fallback: flag sweep + serial atomic chunk loads
                // (old dense row-major layout)
                while (true) {
                    int f1 = __hip_atomic_load(&flags[4 * lane + wv], __ATOMIC_RELAXED,
                                               __HIP_MEMORY_SCOPE_AGENT);
                    int f2 = __hip_atomic_load(&flags[256 + 4 * lane + wv], __ATOMIC_RELAXED,
                                               __HIP_MEMORY_SCOPE_AGENT);
                    u64 m1 = __ballot(f1 >= t);
                    u64 m2 = __ballot(f2 >= t);
                    if ((m1 & m2) == ~0ull) break;
                    __builtin_amdgcn_s_sleep(1);
                }
                asm volatile("" ::: "memory");
                const u16* hp = hring + (size_t)(t & 1) * HBUF_E
                              + (size_t)arow * HD + quad * 8;
                Frag16 bufc[4];
                for (int ci = 0; ci < 8; ++ci) {
                    const int cc = (c0 + ci) & 7;
                    load_chunk_atomic(hp, cc, bufc);
#pragma unroll
                    for (int it = 0; it < 4; ++it) {
                        short8 a  = bufc[it].s8[0];
                        short8 b0 = *(const short8*)(wb0 + 1024 + cc * 128 + it * 32);
                        short8 b1 = *(const short8*)(wb1 + 1024 + cc * 128 + it * 32);
                        a0 = __builtin_amdgcn_mfma_f32_16x16x32_bf16(a, b0, a0, 0, 0, 0);
                        a1 = __builtin_amdgcn_mfma_f32_16x16x32_bf16(a, b1, a1, 0, 0, 0);
                    }
                }
            }
        }

        // ---- dump g to wave-private LDS rows (no cross-wave traffic)
        const int rr = wv * 16 + quad * 4;
#pragma unroll
        for (int i2 = 0; i2 < 4; ++i2) {
            g_lds[(rr + i2) * G_STRIDE + c16]      = a0[i2];
            g_lds[(rr + i2) * G_STRIDE + 16 + c16] = a1[i2];
        }
        asm volatile("s_waitcnt lgkmcnt(0)" ::: "memory");  // wave-internal LDS order

        // ---- gates: wave-local; c-state in registers
        float hv[2], cv[2];
#pragma unroll
        for (int jj = 0; jj < 2; ++jj) {
            int hl = hl0 + jj;
            float gf = g_lds[grow * G_STRIDE + hl]      + bias[jj];
            float gi = g_lds[grow * G_STRIDE + 8 + hl]  + bias[2 + jj];
            float gg = g_lds[grow * G_STRIDE + 16 + hl] + bias[4 + jj];
            float go = g_lds[grow * G_STRIDE + 24 + hl] + bias[6 + jj];
            float fg = sigm(gf), ig = sigm(gi), og = sigm(go);
            float gt = tanh_(gg);
            float cnew = fg * creg[jj] + ig * gt;
            creg[jj] = cnew;
            cv[jj] = cnew;
            hv[jj] = tanh_(cnew) * og;
        }

        if (t < T_STEPS - 1) {
            // h store, write-through u32 (2 bf16) to the coherence point,
            // block-major (R6): this block's slice is a private 1-KB region;
            // each wave writes two FULL 128-B lines -> no partial-line RMW.
            // NO drain, NO flag: the x-GEMM below is the landing window; the
            // consumer's poison check guarantees it never consumes early.
            u32 pk = (u32)(u16)bfb(hv[0]) | ((u32)(u16)bfb(hv[1]) << 16);
            if (ring_on) {
                u16* hn = hring + (size_t)t * HBUF_E;
                __hip_atomic_store((u32*)(hn + (size_t)blk * 512 + grow * 8 + hl0),
                                   pk, __ATOMIC_RELAXED, __HIP_MEMORY_SCOPE_AGENT);
            } else {
                u16* hn = hring + (size_t)((t + 1) & 1) * HBUF_E;
                __hip_atomic_store((u32*)(hn + (size_t)grow * HD + blk * 8 + hl0),
                                   pk, __ATOMIC_RELAXED, __HIP_MEMORY_SCOPE_AGENT);
                // legacy: drain + flag publish (flag protocol needs ordering)
                asm volatile("s_waitcnt vmcnt(0)" ::: "memory");
                if (lane == 0)
                    __hip_atomic_store(&flags[4 * blk + wv], t + 1, __ATOMIC_RELAXED,
                                       __HIP_MEMORY_SCOPE_AGENT);
            }

            // ---- x-side partials for t+1 (fills the store-landing window)
            ax0 = (f32x4){0.f,0.f,0.f,0.f};
            ax1 = (f32x4){0.f,0.f,0.f,0.f};
            if (use16) {
                const u16* xp = x16l + (size_t)(t + 1) * HD;
#pragma unroll 8
                for (int kc = 0; kc < 32; ++kc) {
                    short8 a  = *(const short8*)(xp + kc * 32);
                    short8 b0 = *(const short8*)(wb0 + kc * 32);
                    short8 b1 = *(const short8*)(wb1 + kc * 32);
                    ax0 = __builtin_amdgcn_mfma_f32_16x16x32_bf16(a, b0, ax0, 0, 0, 0);
                    ax1 = __builtin_amdgcn_mfma_f32_16x16x32_bf16(a, b1, ax1, 0, 0, 0);
                }
            } else {
                const float* xp = xf_l + (size_t)(t + 1) * HD;
#pragma unroll 4
                for (int kc = 0; kc < 32; ++kc) {
                    float4 fa = *(const float4*)(xp + kc * 32);
                    float4 fb = *(const float4*)(xp + kc * 32 + 4);
                    short8 a = {bfb(fa.x), bfb(fa.y), bfb(fa.z), bfb(fa.w),
                                bfb(fb.x), bfb(fb.y), bfb(fb.z), bfb(fb.w)};
                    short8 b0 = *(const short8*)(wb0 + kc * 32);
                    short8 b1 = *(const short8*)(wb1 + kc * 32);
                    ax0 = __builtin_amdgcn_mfma_f32_16x16x32_bf16(a, b0, ax0, 0, 0, 0);
                    ax1 = __builtin_amdgcn_mfma_f32_16x16x32_bf16(a, b1, ax1, 0, 0, 0);
                }
            }
        } else {
            // final step: write h_T and c_T (wave-private rows, dense layout)
#pragma unroll
            for (int jj = 0; jj < 2; ++jj) {
                size_t idx = (size_t)grow * HD + blk * 8 + hl0 + jj;
                if (bf16mode) {
                    u16* o = (u16*)outv;
                    __hip_bfloat16 hb = __float2bfloat16(hv[jj]);
                    __hip_bfloat16 cb = __float2bfloat16(cv[jj]);
                    o[idx] = *(u16*)&hb;
                    o[(size_t)BATCH * HD + idx] = *(u16*)&cb;
                } else {
                    float* o = (float*)outv;
                    o[idx] = hv[jj];
                    o[(size_t)BATCH * HD + idx] = cv[jj];
                }
            }
        }
    }
}

extern "C" void kernel_launch(void* const* d_in, const int* in_sizes, int n_in,
                              void* d_out, int out_size, void* d_ws, size_t ws_size,
                              hipStream_t stream) {
    (void)in_sizes; (void)n_in; (void)out_size;
    const void* x   = d_in[0];
    const void* Wii = d_in[1];  const void* Whi = d_in[2];
    const void* Wif = d_in[3];  const void* Whf = d_in[4];
    const void* Wig = d_in[5];  const void* Whg = d_in[6];
    const void* Wio = d_in[7];  const void* Who = d_in[8];
    const void* bii = d_in[9];  const void* bhi = d_in[10];
    const void* bif = d_in[11]; const void* bhf = d_in[12];
    const void* big = d_in[13]; const void* bhg = d_in[14];
    const void* bio = d_in[15]; const void* bho = d_in[16];

    int* flags = (int*)d_ws;                        // legacy-mode flags (2 KB)
    u16* hring = (u16*)((char*)d_ws + 4096);

    const size_t ring_bytes = (size_t)T_STEPS * HBUF_E * 2;          // 64 MiB
    const size_t xb_bytes   = (size_t)BATCH * T_STEPS * HD * 2;      // 64 MiB
    int ring_on = 0;
    u16* xb = nullptr;
    if (ws_size >= 4096 + ring_bytes + xb_bytes) {
        ring_on = 1;
        xb = (u16*)((char*)d_ws + 4096 + ring_bytes);
    } else if (ws_size >= 4096 + ring_bytes) {
        ring_on = 1;                                 // ring, fp32-x direct
    } else if (ws_size >= 4096 + (size_t)2 * HBUF_E * 2 + xb_bytes) {
        xb = (u16*)((char*)d_ws + 4096 + (size_t)2 * HBUF_E * 2);    // legacy
    }

    hipMemsetAsync(d_ws, 0, 4096, stream);
    if (xb)
        hipLaunchKernelGGL(cvt_x_kernel, dim3(2048), dim3(256), 0, stream,
                           x, xb, (BATCH * T_STEPS * HD) / 4);
    if (ring_on)
        hipLaunchKernelGGL(poison_ring_kernel, dim3(2048), dim3(256), 0, stream,
                           (u32x4*)hring, (long)(ring_bytes / 16));

    hipFuncSetAttribute((const void*)lstm_persistent,
                        hipFuncAttributeMaxDynamicSharedMemorySize, SMEM_BYTES);
    hipLaunchKernelGGL(lstm_persistent, dim3(NBLK), dim3(NTHR), SMEM_BYTES, stream,
                       x, Wif, Wii, Wig, Wio, Whf, Whi, Whg, Who,
                       bif, bii, big, bio, bhf, bhi, bhg, bho,
                       hring, ring_on, xb, flags, d_out);
}

// Round 9
// 4818.080 us; speedup vs baseline: 1.2083x; 1.2083x over previous
//
#include <hip/hip_runtime.h>
#include <hip/hip_bf16.h>

typedef unsigned short u16;
typedef unsigned int   u32;
typedef unsigned long long u64;
typedef short short8 __attribute__((ext_vector_type(8)));
typedef float f32x4  __attribute__((ext_vector_type(4)));
typedef u16   u16x4  __attribute__((ext_vector_type(4)));

#define T_STEPS 512
#define BATCH   64
#define HD      1024
#define NBLK    128    // 32 gate-cols per block, 1 block/CU (LDS-bound)
#define NTHR    256
#define NCOL    32
#define WKS     2056   // K-stride in LDS elems: 2048 + 8 pad (16B-aligned)
#define HBUF_E  (BATCH * HD)   // elems per h buffer (128 KB)

// LDS layout (bytes). c-state lives in registers (wave-private rows).
#define W_BYTES    (NCOL * WKS * 2)       // 131584
#define G_OFF      W_BYTES
#define G_STRIDE   33
#define G_BYTES    (BATCH * G_STRIDE * 4) // 8448
#define B_OFF      (G_OFF + G_BYTES)
#define B_BYTES    (NCOL * 4)             // 128
#define F_OFF      (B_OFF + B_BYTES)
#define SMEM_BYTES (F_OFF + 16)           // ~140 KB < 160 KB -> 1 block/CU

__device__ __forceinline__ float sigm(float x) { return 1.f / (1.f + __expf(-x)); }
__device__ __forceinline__ float tanh_(float x) {
    float ax = __builtin_fabsf(x);
    float e  = __expf(-2.f * ax);
    float r  = (1.f - e) / (1.f + e);
    return x < 0.f ? -r : r;
}
__device__ __forceinline__ short bfb(float f) {          // fp32 -> bf16 bits (RNE)
    __hip_bfloat16 h = __float2bfloat16(f);
    return *(short*)&h;
}

// Dtype probe: packed-bf16 x -> low-u16 exponent in [100,140] ~always;
// fp32 x -> mantissa junk, ~uniform. 18-sigma separation at threshold 128.
__device__ int detect_bf16(const u32* __restrict__ x) {
    int c = 0;
#pragma unroll 8
    for (int i = 0; i < 256; ++i) {
        u32 e = (x[i] >> 7) & 0xFF;
        c += (e >= 100 && e <= 140) ? 1 : 0;
    }
    return c >= 128;
}

// Prologue: if x is fp32 and ws has room, pre-convert x -> bf16 once.
extern "C" __global__ void __launch_bounds__(256)
cvt_x_kernel(const void* __restrict__ x, u16* __restrict__ xb, int n4)
{
    __shared__ int flg;
    if (threadIdx.x == 0) flg = detect_bf16((const u32*)x);
    __syncthreads();
    if (flg) return;
    const float4* xf = (const float4*)x;
    u16x4* xo = (u16x4*)xb;
    for (int i = blockIdx.x * blockDim.x + threadIdx.x; i < n4;
         i += gridDim.x * blockDim.x) {
        float4 v = xf[i];
        u16x4 o;
        o[0] = (u16)bfb(v.x); o[1] = (u16)bfb(v.y);
        o[2] = (u16)bfb(v.z); o[3] = (u16)bfb(v.w);
        xo[i] = o;
    }
}

union Frag16 { u64 q[2]; short8 s8[1]; };

// Legacy (non-ring) chunk load: 8-B agent-scope atomic loads from the
// coherence point, OLD dense row-major layout. Correctness fallback only.
__device__ __forceinline__ void load_chunk_atomic(const u16* hp, int c, Frag16* buf) {
#pragma unroll
    for (int it = 0; it < 4; ++it) {
        const u16* ptr = hp + c * 128 + it * 32;
        buf[it].q[0] = __hip_atomic_load((const u64*)ptr, __ATOMIC_RELAXED,
                                         __HIP_MEMORY_SCOPE_AGENT);
        buf[it].q[1] = __hip_atomic_load((const u64*)(ptr + 4), __ATOMIC_RELAXED,
                                         __HIP_MEMORY_SCOPE_AGENT);
    }
}

// ---- forced-issue primitives (T4 / m218 pattern, rule #18) — proven R2/R6 ---
#define LDX(dst, base, OFFSTR) \
    asm volatile("global_load_dwordx4 %0, %1, off offset:" OFFSTR \
                 : "=v"(dst) : "v"(base))

// Block-major ring layout: h[t][kblk][row][8cols], kblk = k/8 (owning block).
// Chunk c covers kblks cc*16..cc*16+16; lane fragment for iter it is
// kblk = cc*16 + it*4 + quad, 16 B at row arow. hp pre-adds quad*512 + arow*8
// (elems). Chunk stride 16 KB; iter stride 4 KB. 13-bit signed imm caps at
// 4095, so two bases with offsets -4096/0.
#define ISSUE_CHUNK(ci) do {                                            \
    const int cc_ = (c0 + (ci)) & 7;                                    \
    u64 bA_ = (u64)(hp + (size_t)cc_ * 8192) + 4096;                    \
    u64 bB_ = bA_ + 8192;                                               \
    LDX(buf[ci][0], bA_, "-4096"); LDX(buf[ci][1], bA_, "0");           \
    LDX(buf[ci][2], bB_, "-4096"); LDX(buf[ci][3], bB_, "0");           \
} while (0)

// Counted drain for chunk ci (4 of its loads retire; rest stay in flight),
// then 8 MFMAs. sched_barrier(0) keeps MFMAs below the waitcnt (rule #18).
#define HCHUNK(ci, VMSTR) do {                                          \
    asm volatile("s_waitcnt vmcnt(" VMSTR ")");                         \
    __builtin_amdgcn_sched_barrier(0);                                  \
    const int cc_ = (c0 + (ci)) & 7;                                    \
    const u16* wA_ = wb0 + 1024 + cc_ * 128;                            \
    const u16* wB_ = wb1 + 1024 + cc_ * 128;                            \
    short8 b0_, b1_;                                                    \
    b0_ = *(const short8*)(wA_);       b1_ = *(const short8*)(wB_);     \
    a0 = __builtin_amdgcn_mfma_f32_16x16x32_bf16(buf[ci][0], b0_, a0, 0, 0, 0); \
    a1 = __builtin_amdgcn_mfma_f32_16x16x32_bf16(buf[ci][0], b1_, a1, 0, 0, 0); \
    b0_ = *(const short8*)(wA_ + 32);  b1_ = *(const short8*)(wB_ + 32);\
    a0 = __builtin_amdgcn_mfma_f32_16x16x32_bf16(buf[ci][1], b0_, a0, 0, 0, 0); \
    a1 = __builtin_amdgcn_mfma_f32_16x16x32_bf16(buf[ci][1], b1_, a1, 0, 0, 0); \
    b0_ = *(const short8*)(wA_ + 64);  b1_ = *(const short8*)(wB_ + 64);\
    a0 = __builtin_amdgcn_mfma_f32_16x16x32_bf16(buf[ci][2], b0_, a0, 0, 0, 0); \
    a1 = __builtin_amdgcn_mfma_f32_16x16x32_bf16(buf[ci][2], b1_, a1, 0, 0, 0); \
    b0_ = *(const short8*)(wA_ + 96);  b1_ = *(const short8*)(wB_ + 96);\
    a0 = __builtin_amdgcn_mfma_f32_16x16x32_bf16(buf[ci][3], b0_, a0, 0, 0, 0); \
    a1 = __builtin_amdgcn_mfma_f32_16x16x32_bf16(buf[ci][3], b1_, a1, 0, 0, 0); \
} while (0)

// x-load blast for step t+1: 32 forced back-to-back dwordx4 (peak outstanding
// 32 < 63). Used ONLY in a straight-line block: issue -> vmcnt(0) -> consume.
// No spin loop, no gates, no backedge inside xr's live range (R3/R8 lesson);
// buf[][] is dead here so registers can be reused, no co-residency.
#define XISSUE(B) do {                                                        \
    LDX(xr[0],(B),"0");    LDX(xr[1],(B),"64");   LDX(xr[2],(B),"128");       \
    LDX(xr[3],(B),"192");  LDX(xr[4],(B),"256");  LDX(xr[5],(B),"320");       \
    LDX(xr[6],(B),"384");  LDX(xr[7],(B),"448");  LDX(xr[8],(B),"512");       \
    LDX(xr[9],(B),"576");  LDX(xr[10],(B),"640"); LDX(xr[11],(B),"704");      \
    LDX(xr[12],(B),"768"); LDX(xr[13],(B),"832"); LDX(xr[14],(B),"896");      \
    LDX(xr[15],(B),"960"); LDX(xr[16],(B),"1024");LDX(xr[17],(B),"1088");     \
    LDX(xr[18],(B),"1152");LDX(xr[19],(B),"1216");LDX(xr[20],(B),"1280");     \
    LDX(xr[21],(B),"1344");LDX(xr[22],(B),"1408");LDX(xr[23],(B),"1472");     \
    LDX(xr[24],(B),"1536");LDX(xr[25],(B),"1600");LDX(xr[26],(B),"1664");     \
    LDX(xr[27],(B),"1728");LDX(xr[28],(B),"1792");LDX(xr[29],(B),"1856");     \
    LDX(xr[30],(B),"1920");LDX(xr[31],(B),"1984");                            \
} while (0)

// x-GEMM from the xr register file: pure LDS reads + MFMA, no VMEM. Replaces
// the load-latency-bound direct version (~6 kcy, measured via R1's convoy
// delta) with issue + ONE parallel RTT + ~1 kcy of MFMA.
#define XGEMM(AX0, AX1) do {                                                  \
    _Pragma("unroll")                                                         \
    for (int kc_ = 0; kc_ < 32; ++kc_) {                                      \
        short8 xb0_ = *(const short8*)(wb0 + kc_ * 32);                       \
        short8 xb1_ = *(const short8*)(wb1 + kc_ * 32);                       \
        AX0 = __builtin_amdgcn_mfma_f32_16x16x32_bf16(xr[kc_], xb0_, AX0, 0, 0, 0); \
        AX1 = __builtin_amdgcn_mfma_f32_16x16x32_bf16(xr[kc_], xb1_, AX1, 0, 0, 0); \
    }                                                                         \
} while (0)

extern "C" __global__ void __launch_bounds__(NTHR, 1)
lstm_persistent(const void* __restrict__ x,
                const void* __restrict__ Wxf, const void* __restrict__ Wxi,
                const void* __restrict__ Wxg, const void* __restrict__ Wxo,
                const void* __restrict__ Whf, const void* __restrict__ Whi,
                const void* __restrict__ Whg, const void* __restrict__ Who,
                const void* __restrict__ bxf, const void* __restrict__ bxi,
                const void* __restrict__ bxg, const void* __restrict__ bxo,
                const void* __restrict__ bhf, const void* __restrict__ bhi,
                const void* __restrict__ bhg, const void* __restrict__ bho,
                u16* __restrict__ hring, int ring_on,
                u16* __restrict__ xb, int* __restrict__ flags,
                void* __restrict__ outv)
{
    // One-time agent acquire: clears L1/L2 of prior-replay ring lines.
    __builtin_amdgcn_fence(__ATOMIC_ACQUIRE, "agent");

    extern __shared__ char smem[];
    u16*   w_lds = (u16*)smem;
    float* g_lds = (float*)(smem + G_OFF);
    float* b_lds = (float*)(smem + B_OFF);
    int*   f_lds = (int*)(smem + F_OFF);

    const int tid = threadIdx.x;
    const int blk = blockIdx.x;

    if (tid == 0) f_lds[0] = detect_bf16((const u32*)x);
    __syncthreads();
    const int bf16mode = f_lds[0];

    // ---- Stage weight slice once (bf16): cols [8*blk, 8*blk+8) of gates f,i,g,o.
    //      LDS: [gate-col][K], K = 1024 x-side then 1024 h-side, k-contiguous.
    {
        const int gate = tid >> 6;   // wave-uniform
        const int kb   = tid & 63;
        const void* WX[4] = {Wxf, Wxi, Wxg, Wxo};
        const void* WH[4] = {Whf, Whi, Whg, Who};
        for (int it = 0; it < 16; ++it) {
            int k = it * 64 + kb;
            u16 vx[8], vh[8];
            if (bf16mode) {
                short8 a = *(const short8*)((const u16*)WX[gate] + (size_t)k * HD + blk * 8);
                short8 b = *(const short8*)((const u16*)WH[gate] + (size_t)k * HD + blk * 8);
#pragma unroll
                for (int ci = 0; ci < 8; ++ci) { vx[ci] = (u16)a[ci]; vh[ci] = (u16)b[ci]; }
            } else {
                const float* px = (const float*)WX[gate] + (size_t)k * HD + blk * 8;
                const float* ph = (const float*)WH[gate] + (size_t)k * HD + blk * 8;
                float4 a0 = *(const float4*)px, a1 = *(const float4*)(px + 4);
                float4 b0 = *(const float4*)ph, b1 = *(const float4*)(ph + 4);
                vx[0]=(u16)bfb(a0.x); vx[1]=(u16)bfb(a0.y); vx[2]=(u16)bfb(a0.z); vx[3]=(u16)bfb(a0.w);
                vx[4]=(u16)bfb(a1.x); vx[5]=(u16)bfb(a1.y); vx[6]=(u16)bfb(a1.z); vx[7]=(u16)bfb(a1.w);
                vh[0]=(u16)bfb(b0.x); vh[1]=(u16)bfb(b0.y); vh[2]=(u16)bfb(b0.z); vh[3]=(u16)bfb(b0.w);
                vh[4]=(u16)bfb(b1.x); vh[5]=(u16)bfb(b1.y); vh[6]=(u16)bfb(b1.z); vh[7]=(u16)bfb(b1.w);
            }
#pragma unroll
            for (int ci = 0; ci < 8; ++ci) {
                w_lds[(gate * 8 + ci) * WKS + k]        = vx[ci];
                w_lds[(gate * 8 + ci) * WKS + 1024 + k] = vh[ci];
            }
        }
    }
    if (tid < NCOL) {
        const void* BX[4] = {bxf, bxi, bxg, bxo};
        const void* BH[4] = {bhf, bhi, bhg, bho};
        int gate = tid >> 3, hc = blk * 8 + (tid & 7);
        float v;
        if (bf16mode)
            v = __bfloat162float(((const __hip_bfloat16*)BX[gate])[hc]) +
                __bfloat162float(((const __hip_bfloat16*)BH[gate])[hc]);
        else
            v = ((const float*)BX[gate])[hc] + ((const float*)BH[gate])[hc];
        b_lds[tid] = v;
    }
    __syncthreads();   // last block-wide sync: w_lds/b_lds now read-only

    // MFMA 16x16x32 bf16: A[m=lane&15][k=quad*8+j], B[k=quad*8+j][n=lane&15],
    // C/D: col=lane&15, row=quad*4+reg  [m89/m91].
    const int wv   = tid >> 6;       // wave = row-class (16 batch rows)
    const int lane = tid & 63;
    const int c16  = lane & 15;
    const int quad = lane >> 4;
    const int arow = wv * 16 + c16;  // batch row this lane loads for A

    const int use16 = bf16mode || (xb != nullptr);
    const u16*   x16l = nullptr;
    const float* xf_l = nullptr;
    if (use16) {
        const u16* x16 = bf16mode ? (const u16*)x : xb;
        x16l = x16 + (size_t)arow * T_STEPS * HD + quad * 8;
    } else {
        xf_l = (const float*)x + (size_t)arow * T_STEPS * HD + quad * 8;
    }
    const u16* wb0 = w_lds + c16 * WKS + quad * 8;         // N-subtile 0: cols 0-15
    const u16* wb1 = w_lds + (16 + c16) * WKS + quad * 8;  // N-subtile 1: cols 16-31

    // gate-phase mapping (wave-private rows): row = wv*16 + (lane>>2),
    // two adjacent local h-cols hl0, hl0+1.
    const int grow = wv * 16 + (lane >> 2);
    const int hl0  = (lane & 3) * 2;
    float bias[8];
#pragma unroll
    for (int g = 0; g < 4; ++g) {
        bias[g * 2]     = b_lds[g * 8 + hl0];
        bias[g * 2 + 1] = b_lds[g * 8 + hl0 + 1];
    }
    float creg[2] = {0.f, 0.f};      // c-state lives in registers (c0 = 0)

    const int c0 = blk >> 4;         // chunk-order rotation (de-burst)
    const int pipe = (ring_on && use16) ? 1 : 0;   // forced x-blast viable

    // x-side partials for t=0 (h-independent)
    f32x4 ax0 = {0.f,0.f,0.f,0.f}, ax1 = {0.f,0.f,0.f,0.f};
    if (use16) {
        const u16* xp = x16l;
#pragma unroll 8
        for (int kc = 0; kc < 32; ++kc) {
            short8 a  = *(const short8*)(xp + kc * 32);
            short8 b0 = *(const short8*)(wb0 + kc * 32);
            short8 b1 = *(const short8*)(wb1 + kc * 32);
            ax0 = __builtin_amdgcn_mfma_f32_16x16x32_bf16(a, b0, ax0, 0, 0, 0);
            ax1 = __builtin_amdgcn_mfma_f32_16x16x32_bf16(a, b1, ax1, 0, 0, 0);
        }
    } else {
        const float* xp = xf_l;
#pragma unroll 4
        for (int kc = 0; kc < 32; ++kc) {
            float4 fa = *(const float4*)(xp + kc * 32);
            float4 fb = *(const float4*)(xp + kc * 32 + 4);
            short8 a = {bfb(fa.x), bfb(fa.y), bfb(fa.z), bfb(fa.w),
                        bfb(fb.x), bfb(fb.y), bfb(fb.z), bfb(fb.w)};
            short8 b0 = *(const short8*)(wb0 + kc * 32);
            short8 b1 = *(const short8*)(wb1 + kc * 32);
            ax0 = __builtin_amdgcn_mfma_f32_16x16x32_bf16(a, b0, ax0, 0, 0, 0);
            ax1 = __builtin_amdgcn_mfma_f32_16x16x32_bf16(a, b1, ax1, 0, 0, 0);
        }
    }

    for (int t = 0; t < T_STEPS; ++t) {
        f32x4 a0 = ax0, a1 = ax1;

        if (t > 0) {
            // ---- all-ready sweep: one pass checks all 128 producer-wave flags
            while (true) {
                int f1 = __hip_atomic_load(&flags[4 * lane + wv], __ATOMIC_RELAXED,
                                           __HIP_MEMORY_SCOPE_AGENT);
                int f2 = __hip_atomic_load(&flags[256 + 4 * lane + wv], __ATOMIC_RELAXED,
                                           __HIP_MEMORY_SCOPE_AGENT);
                u64 m1 = __ballot(f1 >= t);
                u64 m2 = __ballot(f2 >= t);
                if ((m1 & m2) == ~0ull) break;
                __builtin_amdgcn_s_sleep(1);
            }
            asm volatile("" ::: "memory");  // h loads must not precede the poll

            if (ring_on) {
                // Block-major layout base for this lane: quad*512 + arow*8 elems
                const u16* hp = hring + (size_t)(t - 1) * HBUF_E
                              + quad * 512 + arow * 8;
                // ---- forced blast (R6 winner): 32 volatile-asm dwordx4 loads,
                //      counted vmcnt drains chunk-by-chunk.
                short8 buf[8][4];
                asm volatile("s_waitcnt vmcnt(0)");   // invariant: 0 outstanding
                ISSUE_CHUNK(0); ISSUE_CHUNK(1); ISSUE_CHUNK(2); ISSUE_CHUNK(3);
                ISSUE_CHUNK(4); ISSUE_CHUNK(5); ISSUE_CHUNK(6); ISSUE_CHUNK(7);
                HCHUNK(0, "28"); HCHUNK(1, "24"); HCHUNK(2, "20"); HCHUNK(3, "16");
                HCHUNK(4, "12"); HCHUNK(5, "8");  HCHUNK(6, "4");  HCHUNK(7, "0");
            } else {
                // legacy fallback: old dense layout + serial atomic chunk loads
                const u16* hp = hring + (size_t)(t & 1) * HBUF_E
                              + (size_t)arow * HD + quad * 8;
                Frag16 bufc[4];
                for (int ci = 0; ci < 8; ++ci) {
                    const int cc = (c0 + ci) & 7;
                    load_chunk_atomic(hp, cc, bufc);
#pragma unroll
                    for (int it = 0; it < 4; ++it) {
                        short8 a  = bufc[it].s8[0];
                        short8 b0 = *(const short8*)(wb0 + 1024 + cc * 128 + it * 32);
                        short8 b1 = *(const short8*)(wb1 + 1024 + cc * 128 + it * 32);
                        a0 = __builtin_amdgcn_mfma_f32_16x16x32_bf16(a, b0, a0, 0, 0, 0);
                        a1 = __builtin_amdgcn_mfma_f32_16x16x32_bf16(a, b1, a1, 0, 0, 0);
                    }
                }
            }
        }

        // ---- dump g to wave-private LDS rows (no cross-wave traffic)
        const int rr = wv * 16 + quad * 4;
#pragma unroll
        for (int i2 = 0; i2 < 4; ++i2) {
            g_lds[(rr + i2) * G_STRIDE + c16]      = a0[i2];
            g_lds[(rr + i2) * G_STRIDE + 16 + c16] = a1[i2];
        }
        asm volatile("s_waitcnt lgkmcnt(0)" ::: "memory");  // wave-internal LDS order

        // ---- gates: wave-local; c-state in registers
        float hv[2], cv[2];
#pragma unroll
        for (int jj = 0; jj < 2; ++jj) {
            int hl = hl0 + jj;
            float gf = g_lds[grow * G_STRIDE + hl]      + bias[jj];
            float gi = g_lds[grow * G_STRIDE + 8 + hl]  + bias[2 + jj];
            float gg = g_lds[grow * G_STRIDE + 16 + hl] + bias[4 + jj];
            float go = g_lds[grow * G_STRIDE + 24 + hl] + bias[6 + jj];
            float fg = sigm(gf), ig = sigm(gi), og = sigm(go);
            float gt = tanh_(gg);
            float cnew = fg * creg[jj] + ig * gt;
            creg[jj] = cnew;
            cv[jj] = cnew;
            hv[jj] = tanh_(cnew) * og;
        }

        if (t < T_STEPS - 1) {
            // h store, write-through u32 (2 bf16) to the coherence point.
            // Block-major (R6 winner): this block's slice is a private 1-KB
            // region; each wave writes two FULL 128-B lines -> no partial-line
            // RMW, no cross-block line sharing.
            u32 pk = (u32)(u16)bfb(hv[0]) | ((u32)(u16)bfb(hv[1]) << 16);
            if (ring_on) {
                u16* hn = hring + (size_t)t * HBUF_E;
                __hip_atomic_store((u32*)(hn + (size_t)blk * 512 + grow * 8 + hl0),
                                   pk, __ATOMIC_RELAXED, __HIP_MEMORY_SCOPE_AGENT);
            } else {
                u16* hn = hring + (size_t)((t + 1) & 1) * HBUF_E;
                __hip_atomic_store((u32*)(hn + (size_t)grow * HD + blk * 8 + hl0),
                                   pk, __ATOMIC_RELAXED, __HIP_MEMORY_SCOPE_AGENT);
            }
            // wave-local release: drain own vm ops, then publish per-wave flag
            // EARLY (the flag is on the global critical path).
            asm volatile("s_waitcnt vmcnt(0)" ::: "memory");
            if (lane == 0)
                __hip_atomic_store(&flags[4 * blk + wv], t + 1, __ATOMIC_RELAXED,
                                   __HIP_MEMORY_SCOPE_AGENT);

            // ---- x-side partials for t+1 (fills the flag-propagation window).
            ax0 = (f32x4){0.f,0.f,0.f,0.f};
            ax1 = (f32x4){0.f,0.f,0.f,0.f};
            if (pipe) {
                // Forced x-blast: 32 back-to-back loads -> ONE parallel RTT ->
                // pure LDS+MFMA GEMM. xr lifetime is this straight-line block
                // only (no spins/gates/backedge inside; buf is dead; every
                // issue drained in-iteration -> nothing outstanding at endpgm).
                short8 xr[32];
                u64 xb_ = (u64)(x16l + (size_t)(t + 1) * HD);
                XISSUE(xb_);
                asm volatile("s_waitcnt vmcnt(0)");
                __builtin_amdgcn_sched_barrier(0);    // MFMAs stay below drain
                XGEMM(ax0, ax1);
            } else if (use16) {
                const u16* xp = x16l + (size_t)(t + 1) * HD;
#pragma unroll 8
                for (int kc = 0; kc < 32; ++kc) {
                    short8 a  = *(const short8*)(xp + kc * 32);
                    short8 b0 = *(const short8*)(wb0 + kc * 32);
                    short8 b1 = *(const short8*)(wb1 + kc * 32);
                    ax0 = __builtin_amdgcn_mfma_f32_16x16x32_bf16(a, b0, ax0, 0, 0, 0);
                    ax1 = __builtin_amdgcn_mfma_f32_16x16x32_bf16(a, b1, ax1, 0, 0, 0);
                }
            } else {
                const float* xp = xf_l + (size_t)(t + 1) * HD;
#pragma unroll 4
                for (int kc = 0; kc < 32; ++kc) {
                    float4 fa = *(const float4*)(xp + kc * 32);
                    float4 fb = *(const float4*)(xp + kc * 32 + 4);
                    short8 a = {bfb(fa.x), bfb(fa.y), bfb(fa.z), bfb(fa.w),
                                bfb(fb.x), bfb(fb.y), bfb(fb.z), bfb(fb.w)};
                    short8 b0 = *(const short8*)(wb0 + kc * 32);
                    short8 b1 = *(const short8*)(wb1 + kc * 32);
                    ax0 = __builtin_amdgcn_mfma_f32_16x16x32_bf16(a, b0, ax0, 0, 0, 0);
                    ax1 = __builtin_amdgcn_mfma_f32_16x16x32_bf16(a, b1, ax1, 0, 0, 0);
                }
            }
        } else {
            // final step: write h_T and c_T (wave-private rows, dense layout)
#pragma unroll
            for (int jj = 0; jj < 2; ++jj) {
                size_t idx = (size_t)grow * HD + blk * 8 + hl0 + jj;
                if (bf16mode) {
                    u16* o = (u16*)outv;
                    __hip_bfloat16 hb = __float2bfloat16(hv[jj]);
                    __hip_bfloat16 cb = __float2bfloat16(cv[jj]);
                    o[idx] = *(u16*)&hb;
                    o[(size_t)BATCH * HD + idx] = *(u16*)&cb;
                } else {
                    float* o = (float*)outv;
                    o[idx] = hv[jj];
                    o[(size_t)BATCH * HD + idx] = cv[jj];
                }
            }
        }
    }
}

extern "C" void kernel_launch(void* const* d_in, const int* in_sizes, int n_in,
                              void* d_out, int out_size, void* d_ws, size_t ws_size,
                              hipStream_t stream) {
    (void)in_sizes; (void)n_in; (void)out_size;
    const void* x   = d_in[0];
    const void* Wii = d_in[1];  const void* Whi = d_in[2];
    const void* Wif = d_in[3];  const void* Whf = d_in[4];
    const void* Wig = d_in[5];  const void* Whg = d_in[6];
    const void* Wio = d_in[7];  const void* Who = d_in[8];
    const void* bii = d_in[9];  const void* bhi = d_in[10];
    const void* bif = d_in[11]; const void* bhf = d_in[12];
    const void* big = d_in[13]; const void* bhg = d_in[14];
    const void* bio = d_in[15]; const void* bho = d_in[16];

    int* flags = (int*)d_ws;                        // 512 per-wave flags (2 KB)
    u16* hring = (u16*)((char*)d_ws + 4096);

    const size_t ring_bytes = (size_t)T_STEPS * HBUF_E * 2;          // 64 MiB
    const size_t xb_bytes   = (size_t)BATCH * T_STEPS * HD * 2;      // 64 MiB
    int ring_on = 0;
    u16* xb = nullptr;
    if (ws_size >= 4096 + ring_bytes + xb_bytes) {
        ring_on = 1;
        xb = (u16*)((char*)d_ws + 4096 + ring_bytes);
    } else if (ws_size >= 4096 + ring_bytes) {
        ring_on = 1;                                 // ring, fp32-x direct
    } else if (ws_size >= 4096 + (size_t)2 * HBUF_E * 2 + xb_bytes) {
        xb = (u16*)((char*)d_ws + 4096 + (size_t)2 * HBUF_E * 2);    // legacy
    }

    hipMemsetAsync(d_ws, 0, 4096, stream);
    if (xb)
        hipLaunchKernelGGL(cvt_x_kernel, dim3(2048), dim3(256), 0, stream,
                           x, xb, (BATCH * T_STEPS * HD) / 4);

    hipFuncSetAttribute((const void*)lstm_persistent,
                        hipFuncAttributeMaxDynamicSharedMemorySize, SMEM_BYTES);
    hipLaunchKernelGGL(lstm_persistent, dim3(NBLK), dim3(NTHR), SMEM_BYTES, stream,
                       x, Wif, Wii, Wig, Wio, Whf, Whi, Whg, Who,
                       bif, bii, big, bio, bhf, bhi, bhg, bho,
                       hring, ring_on, xb, flags, d_out);
}

// Round 10
// 4074.442 us; speedup vs baseline: 1.4288x; 1.1825x over previous
//
#include <hip/hip_runtime.h>
#include <hip/hip_bf16.h>

typedef unsigned short u16;
typedef unsigned int   u32;
typedef unsigned long long u64;
typedef short short8 __attribute__((ext_vector_type(8)));
typedef float f32x4  __attribute__((ext_vector_type(4)));
typedef u16   u16x4  __attribute__((ext_vector_type(4)));
typedef u32   u32x4  __attribute__((ext_vector_type(4)));

#define T_STEPS 512
#define BATCH   64
#define HD      1024
#define NBLK    128    // 32 gate-cols per block, 1 block/CU (LDS-bound)
#define NTHR    256
#define NCOL    32
#define WKS     2056   // K-stride in LDS elems: 2048 + 8 pad (16B-aligned)
#define HBUF_E  (BATCH * HD)   // elems per h buffer (128 KB)
#define POISON  0xFFFFFFFFu    // two bf16 NaNs; |h|<1 so never produced

// LDS layout (bytes). c-state lives in registers (wave-private rows).
#define W_BYTES    (NCOL * WKS * 2)       // 131584
#define G_OFF      W_BYTES
#define G_STRIDE   33
#define G_BYTES    (BATCH * G_STRIDE * 4) // 8448
#define B_OFF      (G_OFF + G_BYTES)
#define B_BYTES    (NCOL * 4)             // 128
#define F_OFF      (B_OFF + B_BYTES)
#define SMEM_BYTES (F_OFF + 16)           // ~140 KB < 160 KB -> 1 block/CU

__device__ __forceinline__ float sigm(float x) { return 1.f / (1.f + __expf(-x)); }
__device__ __forceinline__ float tanh_(float x) {
    float ax = __builtin_fabsf(x);
    float e  = __expf(-2.f * ax);
    float r  = (1.f - e) / (1.f + e);
    return x < 0.f ? -r : r;
}
__device__ __forceinline__ short bfb(float f) {          // fp32 -> bf16 bits (RNE)
    __hip_bfloat16 h = __float2bfloat16(f);
    return *(short*)&h;
}

// Dtype probe: packed-bf16 x -> low-u16 exponent in [100,140] ~always;
// fp32 x -> mantissa junk, ~uniform. 18-sigma separation at threshold 128.
__device__ int detect_bf16(const u32* __restrict__ x) {
    int c = 0;
#pragma unroll 8
    for (int i = 0; i < 256; ++i) {
        u32 e = (x[i] >> 7) & 0xFF;
        c += (e >= 100 && e <= 140) ? 1 : 0;
    }
    return c >= 128;
}

// Prologue: if x is fp32 and ws has room, pre-convert x -> bf16 once.
extern "C" __global__ void __launch_bounds__(256)
cvt_x_kernel(const void* __restrict__ x, u16* __restrict__ xb, int n4)
{
    __shared__ int flg;
    if (threadIdx.x == 0) flg = detect_bf16((const u32*)x);
    __syncthreads();
    if (flg) return;
    const float4* xf = (const float4*)x;
    u16x4* xo = (u16x4*)xb;
    for (int i = blockIdx.x * blockDim.x + threadIdx.x; i < n4;
         i += gridDim.x * blockDim.x) {
        float4 v = xf[i];
        u16x4 o;
        o[0] = (u16)bfb(v.x); o[1] = (u16)bfb(v.y);
        o[2] = (u16)bfb(v.z); o[3] = (u16)bfb(v.w);
        xo[i] = o;
    }
}

// Poison the h-ring each launch (plain cached stores; the kernel-boundary
// release flush + lstm's entry buffer_inv make them visible). Kills both the
// flag-beats-data race window (backstop sentinel) and the replay hazard.
extern "C" __global__ void __launch_bounds__(256)
poison_ring_kernel(u32x4* __restrict__ ring, long n)
{
    u32x4 p = {POISON, POISON, POISON, POISON};
    for (long i = (long)blockIdx.x * blockDim.x + threadIdx.x; i < n;
         i += (long)gridDim.x * blockDim.x)
        ring[i] = p;
}

union Frag16 { u64 q[2]; short8 s8[1]; };
union HF     { short8 s8; u32 w[4]; u64 q[2]; };

// Legacy (non-ring) chunk load: 8-B agent-scope atomic loads from the
// coherence point, OLD dense row-major layout. Correctness fallback only.
__device__ __forceinline__ void load_chunk_atomic(const u16* hp, int c, Frag16* buf) {
#pragma unroll
    for (int it = 0; it < 4; ++it) {
        const u16* ptr = hp + c * 128 + it * 32;
        buf[it].q[0] = __hip_atomic_load((const u64*)ptr, __ATOMIC_RELAXED,
                                         __HIP_MEMORY_SCOPE_AGENT);
        buf[it].q[1] = __hip_atomic_load((const u64*)(ptr + 4), __ATOMIC_RELAXED,
                                         __HIP_MEMORY_SCOPE_AGENT);
    }
}

// Per-lane: all 16 dwords of this chunk non-poison? Wave-uniform verdict.
// u32 stores are atomic per-dword -> no torn fragments possible.
__device__ __forceinline__ int chunk_clean(const HF* b) {
    u32 ok = 1;
#pragma unroll
    for (int it = 0; it < 4; ++it)
#pragma unroll
        for (int d = 0; d < 4; ++d)
            ok &= (b[it].w[d] != POISON) ? 1u : 0u;
    return __all((int)ok);
}

// ---- forced-issue primitives (T4 / m218 pattern, rule #18) — proven R2/R6 ---
#define LDX(dst, base, OFFSTR) \
    asm volatile("global_load_dwordx4 %0, %1, off offset:" OFFSTR \
                 : "=v"(dst) : "v"(base))

// Block-major ring layout: h[t][kblk][row][8cols], kblk = k/8 (owning block).
// Chunk c covers kblks cc*16..cc*16+16; lane fragment for iter it is
// kblk = cc*16 + it*4 + quad, 16 B at row arow. hp pre-adds quad*512 + arow*8
// (elems). Chunk stride 16 KB; iter stride 4 KB. 13-bit signed imm caps at
// 4095, so two bases with offsets -4096/0.
#define ISSUE_CHUNK(ci) do {                                            \
    const int cc_ = (c0 + (ci)) & 7;                                    \
    u64 bA_ = (u64)(hp + (size_t)cc_ * 8192) + 4096;                    \
    u64 bB_ = bA_ + 8192;                                               \
    LDX(buf[ci][0].s8, bA_, "-4096"); LDX(buf[ci][1].s8, bA_, "0");     \
    LDX(buf[ci][2].s8, bB_, "-4096"); LDX(buf[ci][3].s8, bB_, "0");     \
} while (0)

#define MFMA_CHUNK(ci) do {                                             \
    const int cc_ = (c0 + (ci)) & 7;                                    \
    const u16* wA_ = wb0 + 1024 + cc_ * 128;                            \
    const u16* wB_ = wb1 + 1024 + cc_ * 128;                            \
    short8 b0_, b1_;                                                    \
    b0_ = *(const short8*)(wA_);       b1_ = *(const short8*)(wB_);     \
    a0 = __builtin_amdgcn_mfma_f32_16x16x32_bf16(buf[ci][0].s8, b0_, a0, 0, 0, 0); \
    a1 = __builtin_amdgcn_mfma_f32_16x16x32_bf16(buf[ci][0].s8, b1_, a1, 0, 0, 0); \
    b0_ = *(const short8*)(wA_ + 32);  b1_ = *(const short8*)(wB_ + 32);\
    a0 = __builtin_amdgcn_mfma_f32_16x16x32_bf16(buf[ci][1].s8, b0_, a0, 0, 0, 0); \
    a1 = __builtin_amdgcn_mfma_f32_16x16x32_bf16(buf[ci][1].s8, b1_, a1, 0, 0, 0); \
    b0_ = *(const short8*)(wA_ + 64);  b1_ = *(const short8*)(wB_ + 64);\
    a0 = __builtin_amdgcn_mfma_f32_16x16x32_bf16(buf[ci][2].s8, b0_, a0, 0, 0, 0); \
    a1 = __builtin_amdgcn_mfma_f32_16x16x32_bf16(buf[ci][2].s8, b1_, a1, 0, 0, 0); \
    b0_ = *(const short8*)(wA_ + 96);  b1_ = *(const short8*)(wB_ + 96);\
    a0 = __builtin_amdgcn_mfma_f32_16x16x32_bf16(buf[ci][3].s8, b0_, a0, 0, 0, 0); \
    a1 = __builtin_amdgcn_mfma_f32_16x16x32_bf16(buf[ci][3].s8, b1_, a1, 0, 0, 0); \
} while (0)

// Counted drain for chunk ci, then poison check (~20 cy): clean -> MFMA now,
// dirty (rare: flag beat the data to L3) -> defer to the atomic-retry loop.
#define HCHK(ci, VMSTR) do {                                            \
    asm volatile("s_waitcnt vmcnt(" VMSTR ")");                         \
    __builtin_amdgcn_sched_barrier(0);                                  \
    if (chunk_clean(buf[ci])) { MFMA_CHUNK(ci); }                       \
    else { dirty |= (1u << (ci)); }                                     \
} while (0)

// x-load blast for step t+1: 32 forced back-to-back dwordx4 (peak outstanding
// 32 < 63). Used ONLY in a straight-line block: issue -> vmcnt(0) -> consume.
// No spin loop, no gates, no backedge inside xr's live range (R3/R8 lesson);
// buf[][] is dead here so registers can be reused, no co-residency.
#define XISSUE(B) do {                                                        \
    LDX(xr[0],(B),"0");    LDX(xr[1],(B),"64");   LDX(xr[2],(B),"128");       \
    LDX(xr[3],(B),"192");  LDX(xr[4],(B),"256");  LDX(xr[5],(B),"320");       \
    LDX(xr[6],(B),"384");  LDX(xr[7],(B),"448");  LDX(xr[8],(B),"512");       \
    LDX(xr[9],(B),"576");  LDX(xr[10],(B),"640"); LDX(xr[11],(B),"704");      \
    LDX(xr[12],(B),"768"); LDX(xr[13],(B),"832"); LDX(xr[14],(B),"896");      \
    LDX(xr[15],(B),"960"); LDX(xr[16],(B),"1024");LDX(xr[17],(B),"1088");     \
    LDX(xr[18],(B),"1152");LDX(xr[19],(B),"1216");LDX(xr[20],(B),"1280");     \
    LDX(xr[21],(B),"1344");LDX(xr[22],(B),"1408");LDX(xr[23],(B),"1472");     \
    LDX(xr[24],(B),"1536");LDX(xr[25],(B),"1600");LDX(xr[26],(B),"1664");     \
    LDX(xr[27],(B),"1728");LDX(xr[28],(B),"1792");LDX(xr[29],(B),"1856");     \
    LDX(xr[30],(B),"1920");LDX(xr[31],(B),"1984");                            \
} while (0)

// x-GEMM from the xr register file: pure LDS reads + MFMA, no VMEM.
#define XGEMM(AX0, AX1) do {                                                  \
    _Pragma("unroll")                                                         \
    for (int kc_ = 0; kc_ < 32; ++kc_) {                                      \
        short8 xb0_ = *(const short8*)(wb0 + kc_ * 32);                       \
        short8 xb1_ = *(const short8*)(wb1 + kc_ * 32);                       \
        AX0 = __builtin_amdgcn_mfma_f32_16x16x32_bf16(xr[kc_], xb0_, AX0, 0, 0, 0); \
        AX1 = __builtin_amdgcn_mfma_f32_16x16x32_bf16(xr[kc_], xb1_, AX1, 0, 0, 0); \
    }                                                                         \
} while (0)

extern "C" __global__ void __launch_bounds__(NTHR, 1)
lstm_persistent(const void* __restrict__ x,
                const void* __restrict__ Wxf, const void* __restrict__ Wxi,
                const void* __restrict__ Wxg, const void* __restrict__ Wxo,
                const void* __restrict__ Whf, const void* __restrict__ Whi,
                const void* __restrict__ Whg, const void* __restrict__ Who,
                const void* __restrict__ bxf, const void* __restrict__ bxi,
                const void* __restrict__ bxg, const void* __restrict__ bxo,
                const void* __restrict__ bhf, const void* __restrict__ bhi,
                const void* __restrict__ bhg, const void* __restrict__ bho,
                u16* __restrict__ hring, int ring_on,
                u16* __restrict__ xb, int* __restrict__ flags,
                void* __restrict__ outv)
{
    // One-time agent acquire: clears L1/L2 of poison-fill residue and
    // prior-replay ring lines.
    __builtin_amdgcn_fence(__ATOMIC_ACQUIRE, "agent");

    extern __shared__ char smem[];
    u16*   w_lds = (u16*)smem;
    float* g_lds = (float*)(smem + G_OFF);
    float* b_lds = (float*)(smem + B_OFF);
    int*   f_lds = (int*)(smem + F_OFF);

    const int tid = threadIdx.x;
    const int blk = blockIdx.x;

    if (tid == 0) f_lds[0] = detect_bf16((const u32*)x);
    __syncthreads();
    const int bf16mode = f_lds[0];

    // ---- Stage weight slice once (bf16): cols [8*blk, 8*blk+8) of gates f,i,g,o.
    //      LDS: [gate-col][K], K = 1024 x-side then 1024 h-side, k-contiguous.
    {
        const int gate = tid >> 6;   // wave-uniform
        const int kb   = tid & 63;
        const void* WX[4] = {Wxf, Wxi, Wxg, Wxo};
        const void* WH[4] = {Whf, Whi, Whg, Who};
        for (int it = 0; it < 16; ++it) {
            int k = it * 64 + kb;
            u16 vx[8], vh[8];
            if (bf16mode) {
                short8 a = *(const short8*)((const u16*)WX[gate] + (size_t)k * HD + blk * 8);
                short8 b = *(const short8*)((const u16*)WH[gate] + (size_t)k * HD + blk * 8);
#pragma unroll
                for (int ci = 0; ci < 8; ++ci) { vx[ci] = (u16)a[ci]; vh[ci] = (u16)b[ci]; }
            } else {
                const float* px = (const float*)WX[gate] + (size_t)k * HD + blk * 8;
                const float* ph = (const float*)WH[gate] + (size_t)k * HD + blk * 8;
                float4 a0 = *(const float4*)px, a1 = *(const float4*)(px + 4);
                float4 b0 = *(const float4*)ph, b1 = *(const float4*)(ph + 4);
                vx[0]=(u16)bfb(a0.x); vx[1]=(u16)bfb(a0.y); vx[2]=(u16)bfb(a0.z); vx[3]=(u16)bfb(a0.w);
                vx[4]=(u16)bfb(a1.x); vx[5]=(u16)bfb(a1.y); vx[6]=(u16)bfb(a1.z); vx[7]=(u16)bfb(a1.w);
                vh[0]=(u16)bfb(b0.x); vh[1]=(u16)bfb(b0.y); vh[2]=(u16)bfb(b0.z); vh[3]=(u16)bfb(b0.w);
                vh[4]=(u16)bfb(b1.x); vh[5]=(u16)bfb(b1.y); vh[6]=(u16)bfb(b1.z); vh[7]=(u16)bfb(b1.w);
            }
#pragma unroll
            for (int ci = 0; ci < 8; ++ci) {
                w_lds[(gate * 8 + ci) * WKS + k]        = vx[ci];
                w_lds[(gate * 8 + ci) * WKS + 1024 + k] = vh[ci];
            }
        }
    }
    if (tid < NCOL) {
        const void* BX[4] = {bxf, bxi, bxg, bxo};
        const void* BH[4] = {bhf, bhi, bhg, bho};
        int gate = tid >> 3, hc = blk * 8 + (tid & 7);
        float v;
        if (bf16mode)
            v = __bfloat162float(((const __hip_bfloat16*)BX[gate])[hc]) +
                __bfloat162float(((const __hip_bfloat16*)BH[gate])[hc]);
        else
            v = ((const float*)BX[gate])[hc] + ((const float*)BH[gate])[hc];
        b_lds[tid] = v;
    }
    __syncthreads();   // last block-wide sync: w_lds/b_lds now read-only

    // MFMA 16x16x32 bf16: A[m=lane&15][k=quad*8+j], B[k=quad*8+j][n=lane&15],
    // C/D: col=lane&15, row=quad*4+reg  [m89/m91].
    const int wv   = tid >> 6;       // wave = row-class (16 batch rows)
    const int lane = tid & 63;
    const int c16  = lane & 15;
    const int quad = lane >> 4;
    const int arow = wv * 16 + c16;  // batch row this lane loads for A

    const int use16 = bf16mode || (xb != nullptr);
    const u16*   x16l = nullptr;
    const float* xf_l = nullptr;
    if (use16) {
        const u16* x16 = bf16mode ? (const u16*)x : xb;
        x16l = x16 + (size_t)arow * T_STEPS * HD + quad * 8;
    } else {
        xf_l = (const float*)x + (size_t)arow * T_STEPS * HD + quad * 8;
    }
    const u16* wb0 = w_lds + c16 * WKS + quad * 8;         // N-subtile 0: cols 0-15
    const u16* wb1 = w_lds + (16 + c16) * WKS + quad * 8;  // N-subtile 1: cols 16-31

    // gate-phase mapping (wave-private rows): row = wv*16 + (lane>>2),
    // two adjacent local h-cols hl0, hl0+1.
    const int grow = wv * 16 + (lane >> 2);
    const int hl0  = (lane & 3) * 2;
    float bias[8];
#pragma unroll
    for (int g = 0; g < 4; ++g) {
        bias[g * 2]     = b_lds[g * 8 + hl0];
        bias[g * 2 + 1] = b_lds[g * 8 + hl0 + 1];
    }
    float creg[2] = {0.f, 0.f};      // c-state lives in registers (c0 = 0)

    const int c0 = blk >> 4;         // chunk-order rotation (de-burst)
    const int pipe = (ring_on && use16) ? 1 : 0;   // forced x-blast viable

    // x-side partials for t=0 (h-independent)
    f32x4 ax0 = {0.f,0.f,0.f,0.f}, ax1 = {0.f,0.f,0.f,0.f};
    if (use16) {
        const u16* xp = x16l;
#pragma unroll 8
        for (int kc = 0; kc < 32; ++kc) {
            short8 a  = *(const short8*)(xp + kc * 32);
            short8 b0 = *(const short8*)(wb0 + kc * 32);
            short8 b1 = *(const short8*)(wb1 + kc * 32);
            ax0 = __builtin_amdgcn_mfma_f32_16x16x32_bf16(a, b0, ax0, 0, 0, 0);
            ax1 = __builtin_amdgcn_mfma_f32_16x16x32_bf16(a, b1, ax1, 0, 0, 0);
        }
    } else {
        const float* xp = xf_l;
#pragma unroll 4
        for (int kc = 0; kc < 32; ++kc) {
            float4 fa = *(const float4*)(xp + kc * 32);
            float4 fb = *(const float4*)(xp + kc * 32 + 4);
            short8 a = {bfb(fa.x), bfb(fa.y), bfb(fa.z), bfb(fa.w),
                        bfb(fb.x), bfb(fb.y), bfb(fb.z), bfb(fb.w)};
            short8 b0 = *(const short8*)(wb0 + kc * 32);
            short8 b1 = *(const short8*)(wb1 + kc * 32);
            ax0 = __builtin_amdgcn_mfma_f32_16x16x32_bf16(a, b0, ax0, 0, 0, 0);
            ax1 = __builtin_amdgcn_mfma_f32_16x16x32_bf16(a, b1, ax1, 0, 0, 0);
        }
    }

    for (int t = 0; t < T_STEPS; ++t) {
        f32x4 a0 = ax0, a1 = ax1;

        if (t > 0) {
            // ---- all-ready sweep: one pass checks all 128 producer-wave flags
            while (true) {
                int f1 = __hip_atomic_load(&flags[4 * lane + wv], __ATOMIC_RELAXED,
                                           __HIP_MEMORY_SCOPE_AGENT);
                int f2 = __hip_atomic_load(&flags[256 + 4 * lane + wv], __ATOMIC_RELAXED,
                                           __HIP_MEMORY_SCOPE_AGENT);
                u64 m1 = __ballot(f1 >= t);
                u64 m2 = __ballot(f2 >= t);
                if ((m1 & m2) == ~0ull) break;
                __builtin_amdgcn_s_sleep(1);
            }
            asm volatile("" ::: "memory");  // h loads must not precede the poll

            if (ring_on) {
                // Block-major layout base for this lane: quad*512 + arow*8 elems
                const u16* hp = hring + (size_t)(t - 1) * HBUF_E
                              + quad * 512 + arow * 8;
                // ---- forced blast (R6/R9) + poison backstop: producers now
                //      publish flags WITHOUT a store-ack drain, so on rare
                //      flag-beats-data races a chunk reads poison -> retry via
                //      agent-atomic loads (coherence-point reads, no stale-L2
                //      livelock; progress once the issued stores land).
                HF buf[8][4];
                u32 dirty = 0;
                asm volatile("s_waitcnt vmcnt(0)");   // invariant: 0 outstanding
                ISSUE_CHUNK(0); ISSUE_CHUNK(1); ISSUE_CHUNK(2); ISSUE_CHUNK(3);
                ISSUE_CHUNK(4); ISSUE_CHUNK(5); ISSUE_CHUNK(6); ISSUE_CHUNK(7);
                HCHK(0, "28"); HCHK(1, "24"); HCHK(2, "20"); HCHK(3, "16");
                HCHK(4, "12"); HCHK(5, "8");  HCHK(6, "4");  HCHK(7, "0");
                while (dirty) {                       // wave-uniform mask, rare
#pragma unroll
                    for (int ci = 0; ci < 8; ++ci) {
                        if (dirty & (1u << ci)) {
                            const int cc_ = (c0 + ci) & 7;
#pragma unroll
                            for (int it = 0; it < 4; ++it) {
                                const u16* p = hp + (size_t)cc_ * 8192 + it * 2048;
                                buf[ci][it].q[0] = __hip_atomic_load(
                                    (const u64*)p, __ATOMIC_RELAXED,
                                    __HIP_MEMORY_SCOPE_AGENT);
                                buf[ci][it].q[1] = __hip_atomic_load(
                                    (const u64*)(p + 4), __ATOMIC_RELAXED,
                                    __HIP_MEMORY_SCOPE_AGENT);
                            }
                            if (chunk_clean(buf[ci])) {
                                MFMA_CHUNK(ci);
                                dirty &= ~(1u << ci);
                            }
                        }
                    }
                    if (dirty) __builtin_amdgcn_s_sleep(1);
                }
            } else {
                // legacy fallback: old dense layout + serial atomic chunk loads
                const u16* hp = hring + (size_t)(t & 1) * HBUF_E
                              + (size_t)arow * HD + quad * 8;
                Frag16 bufc[4];
                for (int ci = 0; ci < 8; ++ci) {
                    const int cc = (c0 + ci) & 7;
                    load_chunk_atomic(hp, cc, bufc);
#pragma unroll
                    for (int it = 0; it < 4; ++it) {
                        short8 a  = bufc[it].s8[0];
                        short8 b0 = *(const short8*)(wb0 + 1024 + cc * 128 + it * 32);
                        short8 b1 = *(const short8*)(wb1 + 1024 + cc * 128 + it * 32);
                        a0 = __builtin_amdgcn_mfma_f32_16x16x32_bf16(a, b0, a0, 0, 0, 0);
                        a1 = __builtin_amdgcn_mfma_f32_16x16x32_bf16(a, b1, a1, 0, 0, 0);
                    }
                }
            }
        }

        // ---- dump g to wave-private LDS rows (no cross-wave traffic)
        const int rr = wv * 16 + quad * 4;
#pragma unroll
        for (int i2 = 0; i2 < 4; ++i2) {
            g_lds[(rr + i2) * G_STRIDE + c16]      = a0[i2];
            g_lds[(rr + i2) * G_STRIDE + 16 + c16] = a1[i2];
        }
        asm volatile("s_waitcnt lgkmcnt(0)" ::: "memory");  // wave-internal LDS order

        // ---- gates: wave-local; c-state in registers
        float hv[2], cv[2];
#pragma unroll
        for (int jj = 0; jj < 2; ++jj) {
            int hl = hl0 + jj;
            float gf = g_lds[grow * G_STRIDE + hl]      + bias[jj];
            float gi = g_lds[grow * G_STRIDE + 8 + hl]  + bias[2 + jj];
            float gg = g_lds[grow * G_STRIDE + 16 + hl] + bias[4 + jj];
            float go = g_lds[grow * G_STRIDE + 24 + hl] + bias[6 + jj];
            float fg = sigm(gf), ig = sigm(gi), og = sigm(go);
            float gt = tanh_(gg);
            float cnew = fg * creg[jj] + ig * gt;
            creg[jj] = cnew;
            cv[jj] = cnew;
            hv[jj] = tanh_(cnew) * og;
        }

        if (t < T_STEPS - 1) {
            // h store, write-through u32 (2 bf16) to the coherence point.
            // Block-major (R6): private 1-KB slice, two FULL 128-B lines/wave.
            u32 pk = (u32)(u16)bfb(hv[0]) | ((u32)(u16)bfb(hv[1]) << 16);
            if (ring_on) {
                u16* hn = hring + (size_t)t * HBUF_E;
                __hip_atomic_store((u32*)(hn + (size_t)blk * 512 + grow * 8 + hl0),
                                   pk, __ATOMIC_RELAXED, __HIP_MEMORY_SCOPE_AGENT);
                // NO store-ack drain: publish the flag immediately (saves one
                // full L3 RTT on the convoy-amplified publish chain). Ordering
                // backstop = consumer poison check. The combined vmcnt(0)
                // below (after XISSUE) drains h-stores and x-loads together.
                if (lane == 0)
                    __hip_atomic_store(&flags[4 * blk + wv], t + 1, __ATOMIC_RELAXED,
                                       __HIP_MEMORY_SCOPE_AGENT);
            } else {
                u16* hn = hring + (size_t)((t + 1) & 1) * HBUF_E;
                __hip_atomic_store((u32*)(hn + (size_t)grow * HD + blk * 8 + hl0),
                                   pk, __ATOMIC_RELAXED, __HIP_MEMORY_SCOPE_AGENT);
                // legacy: drain + flag publish (flag protocol needs ordering)
                asm volatile("s_waitcnt vmcnt(0)" ::: "memory");
                if (lane == 0)
                    __hip_atomic_store(&flags[4 * blk + wv], t + 1, __ATOMIC_RELAXED,
                                       __HIP_MEMORY_SCOPE_AGENT);
            }

            // ---- x-side partials for t+1 (fills the flag-propagation window).
            ax0 = (f32x4){0.f,0.f,0.f,0.f};
            ax1 = (f32x4){0.f,0.f,0.f,0.f};
            if (pipe) {
                // Forced x-blast (R9): 32 back-to-back loads -> ONE combined
                // vmcnt(0) (drains h-stores + x-loads in parallel) -> pure
                // LDS+MFMA GEMM. xr lifetime = this straight-line block only.
                short8 xr[32];
                u64 xb_ = (u64)(x16l + (size_t)(t + 1) * HD);
                XISSUE(xb_);
                asm volatile("s_waitcnt vmcnt(0)");
                __builtin_amdgcn_sched_barrier(0);    // MFMAs stay below drain
                XGEMM(ax0, ax1);
            } else if (use16) {
                const u16* xp = x16l + (size_t)(t + 1) * HD;
#pragma unroll 8
                for (int kc = 0; kc < 32; ++kc) {
                    short8 a  = *(const short8*)(xp + kc * 32);
                    short8 b0 = *(const short8*)(wb0 + kc * 32);
                    short8 b1 = *(const short8*)(wb1 + kc * 32);
                    ax0 = __builtin_amdgcn_mfma_f32_16x16x32_bf16(a, b0, ax0, 0, 0, 0);
                    ax1 = __builtin_amdgcn_mfma_f32_16x16x32_bf16(a, b1, ax1, 0, 0, 0);
                }
            } else {
                const float* xp = xf_l + (size_t)(t + 1) * HD;
#pragma unroll 4
                for (int kc = 0; kc < 32; ++kc) {
                    float4 fa = *(const float4*)(xp + kc * 32);
                    float4 fb = *(const float4*)(xp + kc * 32 + 4);
                    short8 a = {bfb(fa.x), bfb(fa.y), bfb(fa.z), bfb(fa.w),
                                bfb(fb.x), bfb(fb.y), bfb(fb.z), bfb(fb.w)};
                    short8 b0 = *(const short8*)(wb0 + kc * 32);
                    short8 b1 = *(const short8*)(wb1 + kc * 32);
                    ax0 = __builtin_amdgcn_mfma_f32_16x16x32_bf16(a, b0, ax0, 0, 0, 0);
                    ax1 = __builtin_amdgcn_mfma_f32_16x16x32_bf16(a, b1, ax1, 0, 0, 0);
                }
            }
        } else {
            // final step: write h_T and c_T (wave-private rows, dense layout)
#pragma unroll
            for (int jj = 0; jj < 2; ++jj) {
                size_t idx = (size_t)grow * HD + blk * 8 + hl0 + jj;
                if (bf16mode) {
                    u16* o = (u16*)outv;
                    __hip_bfloat16 hb = __float2bfloat16(hv[jj]);
                    __hip_bfloat16 cb = __float2bfloat16(cv[jj]);
                    o[idx] = *(u16*)&hb;
                    o[(size_t)BATCH * HD + idx] = *(u16*)&cb;
                } else {
                    float* o = (float*)outv;
                    o[idx] = hv[jj];
                    o[(size_t)BATCH * HD + idx] = cv[jj];
                }
            }
        }
    }
}

extern "C" void kernel_launch(void* const* d_in, const int* in_sizes, int n_in,
                              void* d_out, int out_size, void* d_ws, size_t ws_size,
                              hipStream_t stream) {
    (void)in_sizes; (void)n_in; (void)out_size;
    const void* x   = d_in[0];
    const void* Wii = d_in[1];  const void* Whi = d_in[2];
    const void* Wif = d_in[3];  const void* Whf = d_in[4];
    const void* Wig = d_in[5];  const void* Whg = d_in[6];
    const void* Wio = d_in[7];  const void* Who = d_in[8];
    const void* bii = d_in[9];  const void* bhi = d_in[10];
    const void* bif = d_in[11]; const void* bhf = d_in[12];
    const void* big = d_in[13]; const void* bhg = d_in[14];
    const void* bio = d_in[15]; const void* bho = d_in[16];

    int* flags = (int*)d_ws;                        // 512 per-wave flags (2 KB)
    u16* hring = (u16*)((char*)d_ws + 4096);

    const size_t ring_bytes = (size_t)T_STEPS * HBUF_E * 2;          // 64 MiB
    const size_t xb_bytes   = (size_t)BATCH * T_STEPS * HD * 2;      // 64 MiB
    int ring_on = 0;
    u16* xb = nullptr;
    if (ws_size >= 4096 + ring_bytes + xb_bytes) {
        ring_on = 1;
        xb = (u16*)((char*)d_ws + 4096 + ring_bytes);
    } else if (ws_size >= 4096 + ring_bytes) {
        ring_on = 1;                                 // ring, fp32-x direct
    } else if (ws_size >= 4096 + (size_t)2 * HBUF_E * 2 + xb_bytes) {
        xb = (u16*)((char*)d_ws + 4096 + (size_t)2 * HBUF_E * 2);    // legacy
    }

    hipMemsetAsync(d_ws, 0, 4096, stream);
    if (xb)
        hipLaunchKernelGGL(cvt_x_kernel, dim3(2048), dim3(256), 0, stream,
                           x, xb, (BATCH * T_STEPS * HD) / 4);
    if (ring_on)
        hipLaunchKernelGGL(poison_ring_kernel, dim3(2048), dim3(256), 0, stream,
                           (u32x4*)hring, (long)(ring_bytes / 16));

    hipFuncSetAttribute((const void*)lstm_persistent,
                        hipFuncAttributeMaxDynamicSharedMemorySize, SMEM_BYTES);
    hipLaunchKernelGGL(lstm_persistent, dim3(NBLK), dim3(NTHR), SMEM_BYTES, stream,
                       x, Wif, Wii, Wig, Wio, Whf, Whi, Whg, Who,
                       bif, bii, big, bio, bhf, bhi, bhg, bho,
                       hring, ring_on, xb, flags, d_out);
}